// Round 16
// baseline (195.608 us; speedup 1.0000x reference)
//
#include <hip/hip_runtime.h>

#define N_NODES 100000
#define N_EDGES 1000000
#define EPS 1e-5f
#define SLOPE 0.01f
#define NBUCK 391    // ceil(N/256) buckets of 256 consecutive nodes
#define EPB 2560     // edges per bin block
#define NBINB 391    // bin blocks
#define KSUB 8       // sub-cursors per bucket (blockIdx % 8)
#define SCAP 480     // records per (bucket, sub): mean 320 + 8.9 sigma
#define CCAP 3072    // compacted records per bucket in gather LDS

// ---------------------------------------------------------------------------
// ws layout:
//   Pb   : NBUCK*KSUB*SCAP*32 B (48.0 MB) records, (bucket, sub)-major
//   dl   : NBUCK*KSUB*SCAP*2 B  (3.0 MB)  u16 local dst per record
//   bcur : NBUCK*KSUB ints [zeroed]       sub-cursors
//   stats: 32 floats [zeroed]             sum[16], sumsq[16]
// Measured design rules:
//   r5/r6 : threads/node must not broadcast-duplicate lines (r5) nor
//           replicate the full acc in VGPRs (r6).
//   r8/r9 : grid.sync fusion is NOT coherence-safe on 8-XCD MI355X.
//   r10   : nt stores/L2-bypass regress; plain cached stores optimal.
//   r12-15: same-address atomic RMW = 137 ns; bin = max(chain, copy) solved
//           via 8-way sub-cursors at 391 blocks.
//   r15   : gather at 391x256 = 6 waves/CU (occ 14%) -> latency-starved.
//   r16   : 2 thr/node FEATURE-HALF split: pair loads disjoint 32 B halves
//           of one v-line (no broadcast), acc 80->40 regs (no replication),
//           512-thr blocks -> 12 waves/CU. 16-shfl pair reduce.
// ---------------------------------------------------------------------------

// Kernel 1: bin edges into (bucket, sub)-major staging. (r15, unchanged)
__global__ __launch_bounds__(256) void bin_kernel(
    const float* __restrict__ efeat,
    const int* __restrict__ edge_index,
    int* __restrict__ bcur,
    float4* __restrict__ Pb,
    unsigned short* __restrict__ dl)
{
    __shared__ int s_hist[NBUCK];
    __shared__ int s_base[NBUCK];

    const int tid = threadIdx.x;
    const int ksub = blockIdx.x & (KSUB - 1);
    const int e0 = blockIdx.x * EPB;
    const int e1 = min(e0 + EPB, N_EDGES);

    for (int i = tid; i < NBUCK; i += 256) s_hist[i] = 0;
    __syncthreads();
    for (int eid = e0 + tid; eid < e1; eid += 256) {
        int dst = edge_index[N_EDGES + eid];
        atomicAdd(&s_hist[dst >> 8], 1);
    }
    __syncthreads();

    for (int b = tid; b < NBUCK; b += 256) {
        int c = s_hist[b];
        s_base[b] = c ? atomicAdd(bcur + b * KSUB + ksub, c) : 0;
    }
    __syncthreads();
    for (int i = tid; i < NBUCK; i += 256) s_hist[i] = 0;   // reuse as cursor
    __syncthreads();

    for (int eid = e0 + tid; eid < e1; eid += 256) {
        int src = edge_index[eid];
        int dst = edge_index[N_EDGES + eid];
        float4 ef = *(const float4*)(efeat + (size_t)eid * 4);
        int b = dst >> 8;
        int slot = s_base[b] + atomicAdd(&s_hist[b], 1);
        if (slot < SCAP) {
            size_t rec = ((size_t)b * KSUB + ksub) * SCAP + slot;
            Pb[2 * rec]     = ef;
            Pb[2 * rec + 1] = make_float4(__int_as_float(src), 0.f, 0.f, 0.f);
            dl[rec] = (unsigned short)(dst & 255);
        }
    }
}

// ---------------------------------------------------------------------------
// Kernel 2: per-bucket fused CSR-build + gather + node transform.
// 512 threads; pair (2g, 2g+1) owns node g, lane h = feature-half [8h, 8h+8).
// ---------------------------------------------------------------------------
__global__ __launch_bounds__(512, 4) void gather_bucket_kernel(
    const float* __restrict__ v,
    const float4* __restrict__ Pb,
    const unsigned short* __restrict__ dl,
    const int* __restrict__ bcur,
    const float* __restrict__ enet_w,
    const float* __restrict__ enet_b,
    const float* __restrict__ root,
    const float* __restrict__ bias,
    float* __restrict__ out,
    float* __restrict__ stats)
{
    __shared__ unsigned short s_dl[CCAP];     // 6 KB
    __shared__ unsigned short s_rec[CCAP];    // 6 KB
    __shared__ unsigned short s_perm[CCAP];   // 6 KB
    __shared__ int s_hist[256];
    __shared__ int s_sc[256];
    __shared__ int s_cur[256];
    __shared__ float s_part[8][32];           // 1 KB

    const int b = blockIdx.x;
    const int tid = threadIdx.x;

    // A) segment counts (uniform), compact + histogram (512 threads)
    int ck[KSUB], off[KSUB];
    int cnt = 0;
    #pragma unroll
    for (int k = 0; k < KSUB; ++k) {
        int c = min(bcur[b * KSUB + k], SCAP);
        if (cnt + c > CCAP) c = CCAP - cnt;
        off[k] = cnt;
        ck[k] = c;
        cnt += c;
    }
    if (tid < 256) s_hist[tid] = 0;
    __syncthreads();
    #pragma unroll
    for (int k = 0; k < KSUB; ++k) {
        size_t segbase = ((size_t)b * KSUB + k) * SCAP;
        for (int i = tid; i < ck[k]; i += 512) {
            unsigned short d = dl[segbase + i];
            int pos = off[k] + i;
            s_dl[pos] = d;
            s_rec[pos] = (unsigned short)(k * SCAP + i);
            atomicAdd(&s_hist[d], 1);
        }
    }
    __syncthreads();

    // B) exclusive scan of s_hist (first 256 threads; all hit barriers)
    if (tid < 256) s_sc[tid] = s_hist[tid];
    __syncthreads();
    #pragma unroll
    for (int offs = 1; offs < 256; offs <<= 1) {
        int t = 0;
        if (tid < 256 && tid >= offs) t = s_sc[tid - offs];
        __syncthreads();
        if (tid < 256) s_sc[tid] += t;
        __syncthreads();
    }
    if (tid < 256) s_cur[tid] = s_sc[tid] - s_hist[tid];
    __syncthreads();

    // C) rank: perm[csr_slot] = record index (512 threads)
    for (int i = tid; i < cnt; i += 512) {
        int slot = atomicAdd(&s_cur[s_dl[i]], 1);
        s_perm[slot] = s_rec[i];
    }
    __syncthreads();

    // D) pair gather: lane h accumulates features [8h, 8h+8) of its node.
    const int g = tid >> 1;
    const int h = tid & 1;
    const int n = b * 256 + g;
    const bool active = (n < N_NODES);
    const int deg = s_hist[g];
    const int start = s_sc[g] - deg;

    float acc[40];   // acc[c*8+il]: component c in {1,efx,efy,efz,efw}
    #pragma unroll
    for (int i = 0; i < 40; ++i) acc[i] = 0.0f;

    const float4* pp = Pb + (size_t)2 * ((size_t)b * KSUB * SCAP);
    int j = 0;
    for (; j + 2 <= deg; j += 2) {
        int r0 = s_perm[start + j];
        int r1 = s_perm[start + j + 1];
        float4 ef0 = pp[2*r0], sp0 = pp[2*r0+1];
        float4 ef1 = pp[2*r1], sp1 = pp[2*r1+1];
        int s0 = __float_as_int(sp0.x);
        int s1 = __float_as_int(sp1.x);
        const float4* v0 = (const float4*)(v + (size_t)s0 * 16 + h * 8);
        const float4* v1 = (const float4*)(v + (size_t)s1 * 16 + h * 8);
        float4 a0 = v0[0], a1 = v0[1];     // my 8 features of src0
        float4 b0 = v1[0], b1 = v1[1];     // my 8 features of src1
        acc[ 0] += a0.x + b0.x;  acc[ 1] += a0.y + b0.y;
        acc[ 2] += a0.z + b0.z;  acc[ 3] += a0.w + b0.w;
        acc[ 4] += a1.x + b1.x;  acc[ 5] += a1.y + b1.y;
        acc[ 6] += a1.z + b1.z;  acc[ 7] += a1.w + b1.w;
        #define UPD(c, e0c, e1c) \
            acc[8*(c)+0] = fmaf(e0c, a0.x, fmaf(e1c, b0.x, acc[8*(c)+0])); \
            acc[8*(c)+1] = fmaf(e0c, a0.y, fmaf(e1c, b0.y, acc[8*(c)+1])); \
            acc[8*(c)+2] = fmaf(e0c, a0.z, fmaf(e1c, b0.z, acc[8*(c)+2])); \
            acc[8*(c)+3] = fmaf(e0c, a0.w, fmaf(e1c, b0.w, acc[8*(c)+3])); \
            acc[8*(c)+4] = fmaf(e0c, a1.x, fmaf(e1c, b1.x, acc[8*(c)+4])); \
            acc[8*(c)+5] = fmaf(e0c, a1.y, fmaf(e1c, b1.y, acc[8*(c)+5])); \
            acc[8*(c)+6] = fmaf(e0c, a1.z, fmaf(e1c, b1.z, acc[8*(c)+6])); \
            acc[8*(c)+7] = fmaf(e0c, a1.w, fmaf(e1c, b1.w, acc[8*(c)+7]));
        UPD(1, ef0.x, ef1.x)
        UPD(2, ef0.y, ef1.y)
        UPD(3, ef0.z, ef1.z)
        UPD(4, ef0.w, ef1.w)
        #undef UPD
    }
    if (j < deg) {
        int r0 = s_perm[start + j];
        float4 ef0 = pp[2*r0], sp0 = pp[2*r0+1];
        int s0 = __float_as_int(sp0.x);
        const float4* v0 = (const float4*)(v + (size_t)s0 * 16 + h * 8);
        float4 a0 = v0[0], a1 = v0[1];
        acc[ 0] += a0.x;  acc[ 1] += a0.y;  acc[ 2] += a0.z;  acc[ 3] += a0.w;
        acc[ 4] += a1.x;  acc[ 5] += a1.y;  acc[ 6] += a1.z;  acc[ 7] += a1.w;
        #define UPD1(c, e0c) \
            acc[8*(c)+0] = fmaf(e0c, a0.x, acc[8*(c)+0]); \
            acc[8*(c)+1] = fmaf(e0c, a0.y, acc[8*(c)+1]); \
            acc[8*(c)+2] = fmaf(e0c, a0.z, acc[8*(c)+2]); \
            acc[8*(c)+3] = fmaf(e0c, a0.w, acc[8*(c)+3]); \
            acc[8*(c)+4] = fmaf(e0c, a1.x, acc[8*(c)+4]); \
            acc[8*(c)+5] = fmaf(e0c, a1.y, acc[8*(c)+5]); \
            acc[8*(c)+6] = fmaf(e0c, a1.z, acc[8*(c)+6]); \
            acc[8*(c)+7] = fmaf(e0c, a1.w, acc[8*(c)+7]);
        UPD1(1, ef0.x)
        UPD1(2, ef0.y)
        UPD1(3, ef0.z)
        UPD1(4, ef0.w)
        #undef UPD1
    }

    // contraction over my i-half for ALL 16 outputs, then pair-reduce
    float m[16];
    #pragma unroll
    for (int o = 0; o < 16; ++o) {
        float a = 0.0f;
        #pragma unroll
        for (int il = 0; il < 8; ++il) {
            int i = h * 8 + il;
            a = fmaf(acc[il], enet_b[i * 16 + o], a);            // S0 * B
            #pragma unroll
            for (int k = 0; k < 4; ++k)
                a = fmaf(acc[(k + 1) * 8 + il],
                         enet_w[(i * 16 + o) * 4 + k], a);       // Sk * Wk
        }
        m[o] = a;
    }
    #pragma unroll
    for (int o = 0; o < 16; ++o) m[o] += __shfl_xor(m[o], 1, 64);

    // lane h finishes outputs o = 8h..8h+7: scale + bias + root, write
    float val8[8];
    if (active) {
        float vn[16];
        #pragma unroll
        for (int i = 0; i < 4; ++i) {
            float4 tv = *(const float4*)(v + (size_t)n * 16 + i * 4);
            vn[4*i+0] = tv.x; vn[4*i+1] = tv.y;
            vn[4*i+2] = tv.z; vn[4*i+3] = tv.w;
        }
        float scale = 1.0f / fmaxf((float)deg, 1.0f);
        #pragma unroll
        for (int u = 0; u < 8; ++u) {
            int o = h * 8 + u;
            float a = fmaf(m[o], scale, bias[o]);
            #pragma unroll
            for (int i = 0; i < 16; ++i)
                a = fmaf(vn[i], root[i * 16 + o], a);
            val8[u] = a;
        }
        *(float4*)(out + (size_t)n * 16 + h * 8)     =
            make_float4(val8[0], val8[1], val8[2], val8[3]);
        *(float4*)(out + (size_t)n * 16 + h * 8 + 4) =
            make_float4(val8[4], val8[5], val8[6], val8[7]);
    } else {
        #pragma unroll
        for (int u = 0; u < 8; ++u) val8[u] = 0.0f;
    }

    // stats: butterfly over same-parity lanes (masks 2..32), LDS, atomic
    float s1[8], s2[8];
    #pragma unroll
    for (int u = 0; u < 8; ++u) {
        float a = val8[u];
        float bq = a * a;
        #pragma unroll
        for (int mk = 2; mk < 64; mk <<= 1) {
            a += __shfl_xor(a, mk, 64);
            bq += __shfl_xor(bq, mk, 64);
        }
        s1[u] = a; s2[u] = bq;
    }
    int wave = tid >> 6;
    int lane = tid & 63;
    if (lane < 2) {
        #pragma unroll
        for (int u = 0; u < 8; ++u) {
            s_part[wave][lane * 8 + u]      = s1[u];   // sums o = lane*8+u
            s_part[wave][16 + lane * 8 + u] = s2[u];   // sumsq
        }
    }
    __syncthreads();
    if (tid < 32) {
        float t = 0.0f;
        #pragma unroll
        for (int w = 0; w < 8; ++w) t += s_part[w][tid];
        unsafeAtomicAdd(stats + tid, t);
    }
}

// Kernel 3: BatchNorm (batch stats) + LeakyReLU, in place. (unchanged)
__global__ __launch_bounds__(256) void final_kernel(
    float* __restrict__ out,
    const float* __restrict__ stats,
    const float* __restrict__ gamma,
    const float* __restrict__ beta)
{
    int idx = blockIdx.x * 256 + threadIdx.x;      // float4 index
    if (idx >= N_NODES * 4) return;
    int o0 = (idx & 3) << 2;
    const float invN = 1.0f / (float)N_NODES;
    float4 x = *((const float4*)out + idx);
    float xs[4] = {x.x, x.y, x.z, x.w};
    float r[4];
    #pragma unroll
    for (int u = 0; u < 4; ++u) {
        int o = o0 + u;
        float mu = stats[o] * invN;
        float var = fmaxf(stats[16 + o] * invN - mu * mu, 0.0f);
        float y = fmaf(gamma[o] * (xs[u] - mu), rsqrtf(var + EPS), beta[o]);
        r[u] = (y >= 0.0f) ? y : SLOPE * y;
    }
    *((float4*)out + idx) = make_float4(r[0], r[1], r[2], r[3]);
}

extern "C" void kernel_launch(void* const* d_in, const int* in_sizes, int n_in,
                              void* d_out, int out_size, void* d_ws, size_t ws_size,
                              hipStream_t stream)
{
    const float* v = (const float*)d_in[0];
    const float* e = (const float*)d_in[1];
    const int* edge_index = (const int*)d_in[2];
    const float* enet_w = (const float*)d_in[3];
    const float* enet_b = (const float*)d_in[4];
    const float* root = (const float*)d_in[5];
    const float* bias = (const float*)d_in[6];
    const float* gamma = (const float*)d_in[7];
    const float* beta = (const float*)d_in[8];
    float* out = (float*)d_out;

    char* ws = (char*)d_ws;
    float4*         Pb    = (float4*)ws;  ws += (size_t)NBUCK * KSUB * SCAP * 32;
    unsigned short* dl    = (unsigned short*)ws;
                                          ws += (size_t)NBUCK * KSUB * SCAP * 2;
    int*            bcur  = (int*)ws;     ws += (size_t)NBUCK * KSUB * 4;
    float*          stats = (float*)ws;

    // zero bcur + stats (contiguous, tiny)
    hipMemsetAsync(bcur, 0, (size_t)NBUCK * KSUB * 4 + 32 * 4, stream);

    bin_kernel<<<NBINB, 256, 0, stream>>>(e, edge_index, bcur, Pb, dl);
    gather_bucket_kernel<<<NBUCK, 512, 0, stream>>>(
        v, Pb, dl, bcur, enet_w, enet_b, root, bias, out, stats);
    final_kernel<<<(N_NODES * 4 + 255) / 256, 256, 0, stream>>>(
        out, stats, gamma, beta);
}

// Round 17
// 170.687 us; speedup vs baseline: 1.1460x; 1.1460x over previous
//
#include <hip/hip_runtime.h>

#define N_NODES 100000
#define N_EDGES 1000000
#define EPS 1e-5f
#define SLOPE 0.01f
#define NBUCK 391    // ceil(N/256) buckets of 256 consecutive nodes
#define EPB 2560     // edges per bin block
#define NBINB 391    // bin blocks
#define KSUB 8       // sub-cursors per bucket (blockIdx % 8)
#define SCAP 480     // records per (bucket, sub): mean 320 + 8.9 sigma
#define CCAP 3072    // compacted records per bucket in gather LDS

// ---------------------------------------------------------------------------
// ws layout:
//   pef  : NBUCK*KSUB*SCAP*16 B (24.0 MB) edge features, (bucket, sub)-major
//   meta : NBUCK*KSUB*SCAP*4 B  (6.0 MB)  (src<<8 | dst&255) per record
//   bcur : NBUCK*KSUB ints [zeroed]       sub-cursors
//   stats: 32 floats [zeroed]             sum[16], sumsq[16]
// Measured design rules:
//   r5/r6/r16: splitting a node across lanes loses unless total DISTINCT
//           lines in flight rises (r16: 2x waves x 1/2 lines/wave = wash,
//           minus overhead). 1 thread/node is the right gather shape.
//   r8/r9 : grid.sync fusion is NOT coherence-safe on 8-XCD MI355X.
//   r10   : nt stores/L2-bypass regress; plain cached stores optimal.
//   r12-15: same-address atomic RMW = 137 ns; bin = max(chain, copy);
//           8-way sub-cursors at 391 blocks -> chain ~6.7 us.
//   r17   : meta packed to 4 B; src kept in LDS after phase A. Phase D chain
//           LDS->LDS->v-line (was LDS->32B global record->v-line); ef is an
//           independent 16 B load from an L1/L2-hot 40 KB region.
// ---------------------------------------------------------------------------

// Kernel 1: bin edges into (bucket, sub)-major staging.
__global__ __launch_bounds__(256) void bin_kernel(
    const float* __restrict__ efeat,
    const int* __restrict__ edge_index,
    int* __restrict__ bcur,
    float4* __restrict__ pef,
    unsigned int* __restrict__ meta)
{
    __shared__ int s_hist[NBUCK];
    __shared__ int s_base[NBUCK];

    const int tid = threadIdx.x;
    const int ksub = blockIdx.x & (KSUB - 1);
    const int e0 = blockIdx.x * EPB;
    const int e1 = min(e0 + EPB, N_EDGES);

    for (int i = tid; i < NBUCK; i += 256) s_hist[i] = 0;
    __syncthreads();
    for (int eid = e0 + tid; eid < e1; eid += 256) {
        int dst = edge_index[N_EDGES + eid];
        atomicAdd(&s_hist[dst >> 8], 1);
    }
    __syncthreads();

    for (int b = tid; b < NBUCK; b += 256) {
        int c = s_hist[b];
        s_base[b] = c ? atomicAdd(bcur + b * KSUB + ksub, c) : 0;
    }
    __syncthreads();
    for (int i = tid; i < NBUCK; i += 256) s_hist[i] = 0;   // reuse as cursor
    __syncthreads();

    for (int eid = e0 + tid; eid < e1; eid += 256) {
        int src = edge_index[eid];
        int dst = edge_index[N_EDGES + eid];
        float4 ef = *(const float4*)(efeat + (size_t)eid * 4);
        int b = dst >> 8;
        int slot = s_base[b] + atomicAdd(&s_hist[b], 1);
        if (slot < SCAP) {                      // 8.9-sigma margin; never trips
            size_t rec = ((size_t)b * KSUB + ksub) * SCAP + slot;
            pef[rec]  = ef;
            meta[rec] = ((unsigned)src << 8) | (unsigned)(dst & 255);
        }
    }
}

// ---------------------------------------------------------------------------
// Kernel 2: per-bucket fused CSR-build + gather + node transform.
// 256 threads, 1 thread/node (r15 shape). Phase A streams meta once and
// keeps src in LDS; phase D loads only ef (16 B, hot region) + v-line.
// ---------------------------------------------------------------------------
__global__ __launch_bounds__(256) void gather_bucket_kernel(
    const float* __restrict__ v,
    const float4* __restrict__ pef,
    const unsigned int* __restrict__ meta,
    const int* __restrict__ bcur,
    const float* __restrict__ enet_w,
    const float* __restrict__ enet_b,
    const float* __restrict__ root,
    const float* __restrict__ bias,
    float* __restrict__ out,
    float* __restrict__ stats)
{
    __shared__ int s_src[CCAP];               // 12 KB  src per compact pos
    __shared__ unsigned char s_dl[CCAP];      // 3 KB   local dst per pos
    __shared__ unsigned short s_rec[CCAP];    // 6 KB   record idx per pos
    __shared__ unsigned short s_perm[CCAP];   // 6 KB   compact pos per CSR slot
    __shared__ int s_hist[256];
    __shared__ int s_sc[256];
    __shared__ int s_cur[256];
    __shared__ float s_part[4][32];

    const int b = blockIdx.x;
    const int tid = threadIdx.x;

    // A) segment counts (uniform), compact meta -> LDS + histogram
    int ck[KSUB], off[KSUB];
    int cnt = 0;
    #pragma unroll
    for (int k = 0; k < KSUB; ++k) {
        int c = min(bcur[b * KSUB + k], SCAP);
        if (cnt + c > CCAP) c = CCAP - cnt;
        off[k] = cnt;
        ck[k] = c;
        cnt += c;
    }
    s_hist[tid] = 0;
    __syncthreads();
    #pragma unroll
    for (int k = 0; k < KSUB; ++k) {
        size_t segbase = ((size_t)b * KSUB + k) * SCAP;
        for (int i = tid; i < ck[k]; i += 256) {
            unsigned m = meta[segbase + i];
            int pos = off[k] + i;
            int d = (int)(m & 255u);
            s_src[pos] = (int)(m >> 8);
            s_dl[pos] = (unsigned char)d;
            s_rec[pos] = (unsigned short)(k * SCAP + i);
            atomicAdd(&s_hist[d], 1);
        }
    }
    __syncthreads();

    // B) exclusive scan of s_hist
    int deg = s_hist[tid];
    s_sc[tid] = deg;
    __syncthreads();
    #pragma unroll
    for (int offs = 1; offs < 256; offs <<= 1) {
        int t = (tid >= offs) ? s_sc[tid - offs] : 0;
        __syncthreads();
        s_sc[tid] += t;
        __syncthreads();
    }
    int start = s_sc[tid] - deg;
    s_cur[tid] = start;
    __syncthreads();

    // C) rank: perm[csr_slot] = compact position
    for (int i = tid; i < cnt; i += 256) {
        int slot = atomicAdd(&s_cur[s_dl[i]], 1);
        s_perm[slot] = (unsigned short)i;
    }
    __syncthreads();

    // D) gather, x4 ILP unroll. Chain: LDS perm -> LDS src -> global v-line;
    //    ef loads (via s_rec) are independent 16 B reads from a hot region.
    int n = b * 256 + tid;
    bool active = (n < N_NODES);

    float acc[80];
    #pragma unroll
    for (int i = 0; i < 80; ++i) acc[i] = 0.0f;

    const float4* pp = pef + (size_t)b * KSUB * SCAP;
    int j = 0;
    for (; j + 4 <= deg; j += 4) {
        int p0 = s_perm[start + j + 0];
        int p1 = s_perm[start + j + 1];
        int p2 = s_perm[start + j + 2];
        int p3 = s_perm[start + j + 3];
        int s0 = s_src[p0], s1 = s_src[p1], s2 = s_src[p2], s3 = s_src[p3];
        const float4* vr0 = (const float4*)(v + (size_t)s0 * 16);
        const float4* vr1 = (const float4*)(v + (size_t)s1 * 16);
        const float4* vr2 = (const float4*)(v + (size_t)s2 * 16);
        const float4* vr3 = (const float4*)(v + (size_t)s3 * 16);
        float4 ef0 = pp[s_rec[p0]];
        float4 ef1 = pp[s_rec[p1]];
        float4 ef2 = pp[s_rec[p2]];
        float4 ef3 = pp[s_rec[p3]];
        #pragma unroll
        for (int i = 0; i < 4; ++i) {
            float4 a = vr0[i], bb = vr1[i], c = vr2[i], d = vr3[i];
            acc[     i*4+0] += (a.x + bb.x) + (c.x + d.x);
            acc[     i*4+1] += (a.y + bb.y) + (c.y + d.y);
            acc[     i*4+2] += (a.z + bb.z) + (c.z + d.z);
            acc[     i*4+3] += (a.w + bb.w) + (c.w + d.w);
            acc[16 + i*4+0] = fmaf(ef0.x, a.x, fmaf(ef1.x, bb.x,
                              fmaf(ef2.x, c.x, fmaf(ef3.x, d.x, acc[16 + i*4+0]))));
            acc[16 + i*4+1] = fmaf(ef0.x, a.y, fmaf(ef1.x, bb.y,
                              fmaf(ef2.x, c.y, fmaf(ef3.x, d.y, acc[16 + i*4+1]))));
            acc[16 + i*4+2] = fmaf(ef0.x, a.z, fmaf(ef1.x, bb.z,
                              fmaf(ef2.x, c.z, fmaf(ef3.x, d.z, acc[16 + i*4+2]))));
            acc[16 + i*4+3] = fmaf(ef0.x, a.w, fmaf(ef1.x, bb.w,
                              fmaf(ef2.x, c.w, fmaf(ef3.x, d.w, acc[16 + i*4+3]))));
            acc[32 + i*4+0] = fmaf(ef0.y, a.x, fmaf(ef1.y, bb.x,
                              fmaf(ef2.y, c.x, fmaf(ef3.y, d.x, acc[32 + i*4+0]))));
            acc[32 + i*4+1] = fmaf(ef0.y, a.y, fmaf(ef1.y, bb.y,
                              fmaf(ef2.y, c.y, fmaf(ef3.y, d.y, acc[32 + i*4+1]))));
            acc[32 + i*4+2] = fmaf(ef0.y, a.z, fmaf(ef1.y, bb.z,
                              fmaf(ef2.y, c.z, fmaf(ef3.y, d.z, acc[32 + i*4+2]))));
            acc[32 + i*4+3] = fmaf(ef0.y, a.w, fmaf(ef1.y, bb.w,
                              fmaf(ef2.y, c.w, fmaf(ef3.y, d.w, acc[32 + i*4+3]))));
            acc[48 + i*4+0] = fmaf(ef0.z, a.x, fmaf(ef1.z, bb.x,
                              fmaf(ef2.z, c.x, fmaf(ef3.z, d.x, acc[48 + i*4+0]))));
            acc[48 + i*4+1] = fmaf(ef0.z, a.y, fmaf(ef1.z, bb.y,
                              fmaf(ef2.z, c.y, fmaf(ef3.z, d.y, acc[48 + i*4+1]))));
            acc[48 + i*4+2] = fmaf(ef0.z, a.z, fmaf(ef1.z, bb.z,
                              fmaf(ef2.z, c.z, fmaf(ef3.z, d.z, acc[48 + i*4+2]))));
            acc[48 + i*4+3] = fmaf(ef0.z, a.w, fmaf(ef1.z, bb.w,
                              fmaf(ef2.z, c.w, fmaf(ef3.z, d.w, acc[48 + i*4+3]))));
            acc[64 + i*4+0] = fmaf(ef0.w, a.x, fmaf(ef1.w, bb.x,
                              fmaf(ef2.w, c.x, fmaf(ef3.w, d.x, acc[64 + i*4+0]))));
            acc[64 + i*4+1] = fmaf(ef0.w, a.y, fmaf(ef1.w, bb.y,
                              fmaf(ef2.w, c.y, fmaf(ef3.w, d.y, acc[64 + i*4+1]))));
            acc[64 + i*4+2] = fmaf(ef0.w, a.z, fmaf(ef1.w, bb.z,
                              fmaf(ef2.w, c.z, fmaf(ef3.w, d.z, acc[64 + i*4+2]))));
            acc[64 + i*4+3] = fmaf(ef0.w, a.w, fmaf(ef1.w, bb.w,
                              fmaf(ef2.w, c.w, fmaf(ef3.w, d.w, acc[64 + i*4+3]))));
        }
    }
    for (; j < deg; ++j) {
        int p0 = s_perm[start + j];
        int s0 = s_src[p0];
        const float4* vr = (const float4*)(v + (size_t)s0 * 16);
        float4 ef = pp[s_rec[p0]];
        #pragma unroll
        for (int i = 0; i < 4; ++i) {
            float4 a = vr[i];
            acc[     i*4+0] += a.x;
            acc[     i*4+1] += a.y;
            acc[     i*4+2] += a.z;
            acc[     i*4+3] += a.w;
            acc[16 + i*4+0] = fmaf(ef.x, a.x, acc[16 + i*4+0]);
            acc[16 + i*4+1] = fmaf(ef.x, a.y, acc[16 + i*4+1]);
            acc[16 + i*4+2] = fmaf(ef.x, a.z, acc[16 + i*4+2]);
            acc[16 + i*4+3] = fmaf(ef.x, a.w, acc[16 + i*4+3]);
            acc[32 + i*4+0] = fmaf(ef.y, a.x, acc[32 + i*4+0]);
            acc[32 + i*4+1] = fmaf(ef.y, a.y, acc[32 + i*4+1]);
            acc[32 + i*4+2] = fmaf(ef.y, a.z, acc[32 + i*4+2]);
            acc[32 + i*4+3] = fmaf(ef.y, a.w, acc[32 + i*4+3]);
            acc[48 + i*4+0] = fmaf(ef.z, a.x, acc[48 + i*4+0]);
            acc[48 + i*4+1] = fmaf(ef.z, a.y, acc[48 + i*4+1]);
            acc[48 + i*4+2] = fmaf(ef.z, a.z, acc[48 + i*4+2]);
            acc[48 + i*4+3] = fmaf(ef.z, a.w, acc[48 + i*4+3]);
            acc[64 + i*4+0] = fmaf(ef.w, a.x, acc[64 + i*4+0]);
            acc[64 + i*4+1] = fmaf(ef.w, a.y, acc[64 + i*4+1]);
            acc[64 + i*4+2] = fmaf(ef.w, a.z, acc[64 + i*4+2]);
            acc[64 + i*4+3] = fmaf(ef.w, a.w, acc[64 + i*4+3]);
        }
    }

    float val[16];
    if (active) {
        float vn[16];
        #pragma unroll
        for (int i = 0; i < 4; ++i) {
            float4 tv = *(const float4*)(v + (size_t)n * 16 + i * 4);
            vn[4*i+0] = tv.x; vn[4*i+1] = tv.y;
            vn[4*i+2] = tv.z; vn[4*i+3] = tv.w;
        }
        float scale = 1.0f / fmaxf((float)deg, 1.0f);
        #pragma unroll
        for (int o = 0; o < 16; ++o) {
            float a = 0.0f;
            #pragma unroll
            for (int i = 0; i < 16; ++i) {
                a = fmaf(acc[i], enet_b[i * 16 + o], a);           // S0 * B
                #pragma unroll
                for (int k = 0; k < 4; ++k)
                    a = fmaf(acc[16 + k * 16 + i],
                             enet_w[(i * 16 + o) * 4 + k], a);     // Sk * Wk
            }
            a = fmaf(a, scale, bias[o]);
            #pragma unroll
            for (int i = 0; i < 16; ++i)
                a = fmaf(vn[i], root[i * 16 + o], a);
            val[o] = a;
        }
        #pragma unroll
        for (int i = 0; i < 4; ++i)
            *(float4*)(out + (size_t)n * 16 + i * 4) =
                make_float4(val[4*i+0], val[4*i+1], val[4*i+2], val[4*i+3]);
    } else {
        #pragma unroll
        for (int o = 0; o < 16; ++o) val[o] = 0.0f;
    }

    // batch-stat reduction: wave butterfly -> LDS -> device atomic
    float ssum[16], ssq[16];
    #pragma unroll
    for (int o = 0; o < 16; ++o) {
        float a = val[o];
        float bsq = a * a;
        #pragma unroll
        for (int m = 1; m < 64; m <<= 1) {
            a += __shfl_xor(a, m, 64);
            bsq += __shfl_xor(bsq, m, 64);
        }
        ssum[o] = a; ssq[o] = bsq;
    }
    int wave = tid >> 6;
    int lane = tid & 63;
    if (lane == 0) {
        #pragma unroll
        for (int o = 0; o < 16; ++o) {
            s_part[wave][o]      = ssum[o];
            s_part[wave][16 + o] = ssq[o];
        }
    }
    __syncthreads();
    if (tid < 32) {
        float t = s_part[0][tid] + s_part[1][tid] +
                  s_part[2][tid] + s_part[3][tid];
        unsafeAtomicAdd(stats + tid, t);
    }
}

// Kernel 3: BatchNorm (batch stats) + LeakyReLU, in place. (unchanged)
__global__ __launch_bounds__(256) void final_kernel(
    float* __restrict__ out,
    const float* __restrict__ stats,
    const float* __restrict__ gamma,
    const float* __restrict__ beta)
{
    int idx = blockIdx.x * 256 + threadIdx.x;      // float4 index
    if (idx >= N_NODES * 4) return;
    int o0 = (idx & 3) << 2;
    const float invN = 1.0f / (float)N_NODES;
    float4 x = *((const float4*)out + idx);
    float xs[4] = {x.x, x.y, x.z, x.w};
    float r[4];
    #pragma unroll
    for (int u = 0; u < 4; ++u) {
        int o = o0 + u;
        float mu = stats[o] * invN;
        float var = fmaxf(stats[16 + o] * invN - mu * mu, 0.0f);
        float y = fmaf(gamma[o] * (xs[u] - mu), rsqrtf(var + EPS), beta[o]);
        r[u] = (y >= 0.0f) ? y : SLOPE * y;
    }
    *((float4*)out + idx) = make_float4(r[0], r[1], r[2], r[3]);
}

extern "C" void kernel_launch(void* const* d_in, const int* in_sizes, int n_in,
                              void* d_out, int out_size, void* d_ws, size_t ws_size,
                              hipStream_t stream)
{
    const float* v = (const float*)d_in[0];
    const float* e = (const float*)d_in[1];
    const int* edge_index = (const int*)d_in[2];
    const float* enet_w = (const float*)d_in[3];
    const float* enet_b = (const float*)d_in[4];
    const float* root = (const float*)d_in[5];
    const float* bias = (const float*)d_in[6];
    const float* gamma = (const float*)d_in[7];
    const float* beta = (const float*)d_in[8];
    float* out = (float*)d_out;

    char* ws = (char*)d_ws;
    float4*       pef   = (float4*)ws;    ws += (size_t)NBUCK * KSUB * SCAP * 16;
    unsigned int* meta  = (unsigned int*)ws;
                                          ws += (size_t)NBUCK * KSUB * SCAP * 4;
    int*          bcur  = (int*)ws;       ws += (size_t)NBUCK * KSUB * 4;
    float*        stats = (float*)ws;

    // zero bcur + stats (contiguous, tiny)
    hipMemsetAsync(bcur, 0, (size_t)NBUCK * KSUB * 4 + 32 * 4, stream);

    bin_kernel<<<NBINB, 256, 0, stream>>>(e, edge_index, bcur, pef, meta);
    gather_bucket_kernel<<<NBUCK, 256, 0, stream>>>(
        v, pef, meta, bcur, enet_w, enet_b, root, bias, out, stats);
    final_kernel<<<(N_NODES * 4 + 255) / 256, 256, 0, stream>>>(
        out, stats, gamma, beta);
}

// Round 18
// 169.335 us; speedup vs baseline: 1.1552x; 1.0080x over previous
//
#include <hip/hip_runtime.h>

#define N_NODES 100000
#define N_EDGES 1000000
#define EPS 1e-5f
#define SLOPE 0.01f
#define NBUCK 391    // ceil(N/256) buckets of 256 consecutive nodes
#define EPB 2560     // edges per bin block
#define NBINB 391    // bin blocks
#define KSUB 8       // sub-cursors per bucket (blockIdx % 8)
#define SCAP 480     // records per (bucket, sub): mean 320 + 8.9 sigma
#define CCAP 3072    // compacted records per bucket in gather LDS

// ---------------------------------------------------------------------------
// ws layout:
//   pef  : NBUCK*KSUB*SCAP*16 B (24.0 MB) edge features, (bucket, sub)-major
//   meta : NBUCK*KSUB*SCAP*4 B  (6.0 MB)  (src<<8 | dst&255) per record
//   bcur : NBUCK*KSUB ints [zeroed]       sub-cursors
//   stats: 32 floats [zeroed]             sum[16], sumsq[16]
// Measured design rules:
//   r5/r6/r16: 1 thread/node is the right gather shape (all lane-splits lose).
//   r8/r9 : grid.sync fusion is NOT coherence-safe on 8-XCD MI355X.
//   r10   : nt stores/L2-bypass regress; plain cached stores optimal.
//   r12-15: same-address atomic RMW = 137 ns; bin = max(chain, copy);
//           8-way sub-cursors at 391 blocks.
//   r17   : 20 B/edge bin format good (bin faster, FETCH -13 MB) but perm->
//           src->rec scattered dependent LDS chain cost gather 54->78 us
//           (bank conflicts 245k->400k, hbm 1.4->0.8 TB/s).
//   r18   : phase C writes SORTED payload s_metaS[slot]=src*4096+rec; phase D
//           front-end = one contiguous independent LDS round, then 8 globals.
// ---------------------------------------------------------------------------

// Kernel 1: bin edges into (bucket, sub)-major staging. (r17, unchanged)
__global__ __launch_bounds__(256) void bin_kernel(
    const float* __restrict__ efeat,
    const int* __restrict__ edge_index,
    int* __restrict__ bcur,
    float4* __restrict__ pef,
    unsigned int* __restrict__ meta)
{
    __shared__ int s_hist[NBUCK];
    __shared__ int s_base[NBUCK];

    const int tid = threadIdx.x;
    const int ksub = blockIdx.x & (KSUB - 1);
    const int e0 = blockIdx.x * EPB;
    const int e1 = min(e0 + EPB, N_EDGES);

    for (int i = tid; i < NBUCK; i += 256) s_hist[i] = 0;
    __syncthreads();
    for (int eid = e0 + tid; eid < e1; eid += 256) {
        int dst = edge_index[N_EDGES + eid];
        atomicAdd(&s_hist[dst >> 8], 1);
    }
    __syncthreads();

    for (int b = tid; b < NBUCK; b += 256) {
        int c = s_hist[b];
        s_base[b] = c ? atomicAdd(bcur + b * KSUB + ksub, c) : 0;
    }
    __syncthreads();
    for (int i = tid; i < NBUCK; i += 256) s_hist[i] = 0;   // reuse as cursor
    __syncthreads();

    for (int eid = e0 + tid; eid < e1; eid += 256) {
        int src = edge_index[eid];
        int dst = edge_index[N_EDGES + eid];
        float4 ef = *(const float4*)(efeat + (size_t)eid * 4);
        int b = dst >> 8;
        int slot = s_base[b] + atomicAdd(&s_hist[b], 1);
        if (slot < SCAP) {                      // 8.9-sigma margin; never trips
            size_t rec = ((size_t)b * KSUB + ksub) * SCAP + slot;
            pef[rec]  = ef;
            meta[rec] = ((unsigned)src << 8) | (unsigned)(dst & 255);
        }
    }
}

// ---------------------------------------------------------------------------
// Kernel 2: per-bucket fused CSR-build + gather + node transform.
// Phase C materializes the SORTED payload (src*4096+rec per CSR slot) so
// phase D's front-end is a single contiguous LDS read round per chunk.
// ---------------------------------------------------------------------------
__global__ __launch_bounds__(256) void gather_bucket_kernel(
    const float* __restrict__ v,
    const float4* __restrict__ pef,
    const unsigned int* __restrict__ meta,
    const int* __restrict__ bcur,
    const float* __restrict__ enet_w,
    const float* __restrict__ enet_b,
    const float* __restrict__ root,
    const float* __restrict__ bias,
    float* __restrict__ out,
    float* __restrict__ stats)
{
    __shared__ unsigned int s_metaA[CCAP];    // 12 KB  src*4096+rec, compact
    __shared__ unsigned char s_dl[CCAP];      // 3 KB   local dst, compact
    __shared__ unsigned int s_metaS[CCAP];    // 12 KB  src*4096+rec, CSR order
    __shared__ int s_hist[256];
    __shared__ int s_sc[256];
    __shared__ int s_cur[256];
    __shared__ float s_part[4][32];

    const int b = blockIdx.x;
    const int tid = threadIdx.x;

    // A) segment counts (uniform), compact meta -> LDS + histogram
    int ck[KSUB], off[KSUB];
    int cnt = 0;
    #pragma unroll
    for (int k = 0; k < KSUB; ++k) {
        int c = min(bcur[b * KSUB + k], SCAP);
        if (cnt + c > CCAP) c = CCAP - cnt;
        off[k] = cnt;
        ck[k] = c;
        cnt += c;
    }
    s_hist[tid] = 0;
    __syncthreads();
    #pragma unroll
    for (int k = 0; k < KSUB; ++k) {
        size_t segbase = ((size_t)b * KSUB + k) * SCAP;
        for (int i = tid; i < ck[k]; i += 256) {
            unsigned m = meta[segbase + i];
            int pos = off[k] + i;
            int d = (int)(m & 255u);
            s_metaA[pos] = (m >> 8) * 4096u + (unsigned)(k * SCAP + i);
            s_dl[pos] = (unsigned char)d;
            atomicAdd(&s_hist[d], 1);
        }
    }
    __syncthreads();

    // B) exclusive scan of s_hist
    int deg = s_hist[tid];
    s_sc[tid] = deg;
    __syncthreads();
    #pragma unroll
    for (int offs = 1; offs < 256; offs <<= 1) {
        int t = (tid >= offs) ? s_sc[tid - offs] : 0;
        __syncthreads();
        s_sc[tid] += t;
        __syncthreads();
    }
    int start = s_sc[tid] - deg;
    s_cur[tid] = start;
    __syncthreads();

    // C) scatter SORTED payload: s_metaS[csr_slot] = src*4096+rec
    for (int i = tid; i < cnt; i += 256) {
        int slot = atomicAdd(&s_cur[s_dl[i]], 1);
        s_metaS[slot] = s_metaA[i];
    }
    __syncthreads();

    // D) gather, x4 ILP unroll. Front-end per chunk: 4 CONTIGUOUS independent
    //    LDS reads -> decode -> 8 independent global loads (4 v-lines + 4 ef).
    int n = b * 256 + tid;
    bool active = (n < N_NODES);

    float acc[80];
    #pragma unroll
    for (int i = 0; i < 80; ++i) acc[i] = 0.0f;

    const float4* pp = pef + (size_t)b * KSUB * SCAP;
    int j = 0;
    for (; j + 4 <= deg; j += 4) {
        unsigned m0 = s_metaS[start + j + 0];
        unsigned m1 = s_metaS[start + j + 1];
        unsigned m2 = s_metaS[start + j + 2];
        unsigned m3 = s_metaS[start + j + 3];
        int s0 = (int)(m0 >> 12), r0 = (int)(m0 & 4095u);
        int s1 = (int)(m1 >> 12), r1 = (int)(m1 & 4095u);
        int s2 = (int)(m2 >> 12), r2 = (int)(m2 & 4095u);
        int s3 = (int)(m3 >> 12), r3 = (int)(m3 & 4095u);
        const float4* vr0 = (const float4*)(v + (size_t)s0 * 16);
        const float4* vr1 = (const float4*)(v + (size_t)s1 * 16);
        const float4* vr2 = (const float4*)(v + (size_t)s2 * 16);
        const float4* vr3 = (const float4*)(v + (size_t)s3 * 16);
        float4 ef0 = pp[r0];
        float4 ef1 = pp[r1];
        float4 ef2 = pp[r2];
        float4 ef3 = pp[r3];
        #pragma unroll
        for (int i = 0; i < 4; ++i) {
            float4 a = vr0[i], bb = vr1[i], c = vr2[i], d = vr3[i];
            acc[     i*4+0] += (a.x + bb.x) + (c.x + d.x);
            acc[     i*4+1] += (a.y + bb.y) + (c.y + d.y);
            acc[     i*4+2] += (a.z + bb.z) + (c.z + d.z);
            acc[     i*4+3] += (a.w + bb.w) + (c.w + d.w);
            acc[16 + i*4+0] = fmaf(ef0.x, a.x, fmaf(ef1.x, bb.x,
                              fmaf(ef2.x, c.x, fmaf(ef3.x, d.x, acc[16 + i*4+0]))));
            acc[16 + i*4+1] = fmaf(ef0.x, a.y, fmaf(ef1.x, bb.y,
                              fmaf(ef2.x, c.y, fmaf(ef3.x, d.y, acc[16 + i*4+1]))));
            acc[16 + i*4+2] = fmaf(ef0.x, a.z, fmaf(ef1.x, bb.z,
                              fmaf(ef2.x, c.z, fmaf(ef3.x, d.z, acc[16 + i*4+2]))));
            acc[16 + i*4+3] = fmaf(ef0.x, a.w, fmaf(ef1.x, bb.w,
                              fmaf(ef2.x, c.w, fmaf(ef3.x, d.w, acc[16 + i*4+3]))));
            acc[32 + i*4+0] = fmaf(ef0.y, a.x, fmaf(ef1.y, bb.x,
                              fmaf(ef2.y, c.x, fmaf(ef3.y, d.x, acc[32 + i*4+0]))));
            acc[32 + i*4+1] = fmaf(ef0.y, a.y, fmaf(ef1.y, bb.y,
                              fmaf(ef2.y, c.y, fmaf(ef3.y, d.y, acc[32 + i*4+1]))));
            acc[32 + i*4+2] = fmaf(ef0.y, a.z, fmaf(ef1.y, bb.z,
                              fmaf(ef2.y, c.z, fmaf(ef3.y, d.z, acc[32 + i*4+2]))));
            acc[32 + i*4+3] = fmaf(ef0.y, a.w, fmaf(ef1.y, bb.w,
                              fmaf(ef2.y, c.w, fmaf(ef3.y, d.w, acc[32 + i*4+3]))));
            acc[48 + i*4+0] = fmaf(ef0.z, a.x, fmaf(ef1.z, bb.x,
                              fmaf(ef2.z, c.x, fmaf(ef3.z, d.x, acc[48 + i*4+0]))));
            acc[48 + i*4+1] = fmaf(ef0.z, a.y, fmaf(ef1.z, bb.y,
                              fmaf(ef2.z, c.y, fmaf(ef3.z, d.y, acc[48 + i*4+1]))));
            acc[48 + i*4+2] = fmaf(ef0.z, a.z, fmaf(ef1.z, bb.z,
                              fmaf(ef2.z, c.z, fmaf(ef3.z, d.z, acc[48 + i*4+2]))));
            acc[48 + i*4+3] = fmaf(ef0.z, a.w, fmaf(ef1.z, bb.w,
                              fmaf(ef2.z, c.w, fmaf(ef3.z, d.w, acc[48 + i*4+3]))));
            acc[64 + i*4+0] = fmaf(ef0.w, a.x, fmaf(ef1.w, bb.x,
                              fmaf(ef2.w, c.x, fmaf(ef3.w, d.x, acc[64 + i*4+0]))));
            acc[64 + i*4+1] = fmaf(ef0.w, a.y, fmaf(ef1.w, bb.y,
                              fmaf(ef2.w, c.y, fmaf(ef3.w, d.y, acc[64 + i*4+1]))));
            acc[64 + i*4+2] = fmaf(ef0.w, a.z, fmaf(ef1.w, bb.z,
                              fmaf(ef2.w, c.z, fmaf(ef3.w, d.z, acc[64 + i*4+2]))));
            acc[64 + i*4+3] = fmaf(ef0.w, a.w, fmaf(ef1.w, bb.w,
                              fmaf(ef2.w, c.w, fmaf(ef3.w, d.w, acc[64 + i*4+3]))));
        }
    }
    for (; j < deg; ++j) {
        unsigned m0 = s_metaS[start + j];
        int s0 = (int)(m0 >> 12), r0 = (int)(m0 & 4095u);
        const float4* vr = (const float4*)(v + (size_t)s0 * 16);
        float4 ef = pp[r0];
        #pragma unroll
        for (int i = 0; i < 4; ++i) {
            float4 a = vr[i];
            acc[     i*4+0] += a.x;
            acc[     i*4+1] += a.y;
            acc[     i*4+2] += a.z;
            acc[     i*4+3] += a.w;
            acc[16 + i*4+0] = fmaf(ef.x, a.x, acc[16 + i*4+0]);
            acc[16 + i*4+1] = fmaf(ef.x, a.y, acc[16 + i*4+1]);
            acc[16 + i*4+2] = fmaf(ef.x, a.z, acc[16 + i*4+2]);
            acc[16 + i*4+3] = fmaf(ef.x, a.w, acc[16 + i*4+3]);
            acc[32 + i*4+0] = fmaf(ef.y, a.x, acc[32 + i*4+0]);
            acc[32 + i*4+1] = fmaf(ef.y, a.y, acc[32 + i*4+1]);
            acc[32 + i*4+2] = fmaf(ef.y, a.z, acc[32 + i*4+2]);
            acc[32 + i*4+3] = fmaf(ef.y, a.w, acc[32 + i*4+3]);
            acc[48 + i*4+0] = fmaf(ef.z, a.x, acc[48 + i*4+0]);
            acc[48 + i*4+1] = fmaf(ef.z, a.y, acc[48 + i*4+1]);
            acc[48 + i*4+2] = fmaf(ef.z, a.z, acc[48 + i*4+2]);
            acc[48 + i*4+3] = fmaf(ef.z, a.w, acc[48 + i*4+3]);
            acc[64 + i*4+0] = fmaf(ef.w, a.x, acc[64 + i*4+0]);
            acc[64 + i*4+1] = fmaf(ef.w, a.y, acc[64 + i*4+1]);
            acc[64 + i*4+2] = fmaf(ef.w, a.z, acc[64 + i*4+2]);
            acc[64 + i*4+3] = fmaf(ef.w, a.w, acc[64 + i*4+3]);
        }
    }

    float val[16];
    if (active) {
        float vn[16];
        #pragma unroll
        for (int i = 0; i < 4; ++i) {
            float4 tv = *(const float4*)(v + (size_t)n * 16 + i * 4);
            vn[4*i+0] = tv.x; vn[4*i+1] = tv.y;
            vn[4*i+2] = tv.z; vn[4*i+3] = tv.w;
        }
        float scale = 1.0f / fmaxf((float)deg, 1.0f);
        #pragma unroll
        for (int o = 0; o < 16; ++o) {
            float a = 0.0f;
            #pragma unroll
            for (int i = 0; i < 16; ++i) {
                a = fmaf(acc[i], enet_b[i * 16 + o], a);           // S0 * B
                #pragma unroll
                for (int k = 0; k < 4; ++k)
                    a = fmaf(acc[16 + k * 16 + i],
                             enet_w[(i * 16 + o) * 4 + k], a);     // Sk * Wk
            }
            a = fmaf(a, scale, bias[o]);
            #pragma unroll
            for (int i = 0; i < 16; ++i)
                a = fmaf(vn[i], root[i * 16 + o], a);
            val[o] = a;
        }
        #pragma unroll
        for (int i = 0; i < 4; ++i)
            *(float4*)(out + (size_t)n * 16 + i * 4) =
                make_float4(val[4*i+0], val[4*i+1], val[4*i+2], val[4*i+3]);
    } else {
        #pragma unroll
        for (int o = 0; o < 16; ++o) val[o] = 0.0f;
    }

    // batch-stat reduction: wave butterfly -> LDS -> device atomic
    float ssum[16], ssq[16];
    #pragma unroll
    for (int o = 0; o < 16; ++o) {
        float a = val[o];
        float bsq = a * a;
        #pragma unroll
        for (int m = 1; m < 64; m <<= 1) {
            a += __shfl_xor(a, m, 64);
            bsq += __shfl_xor(bsq, m, 64);
        }
        ssum[o] = a; ssq[o] = bsq;
    }
    int wave = tid >> 6;
    int lane = tid & 63;
    if (lane == 0) {
        #pragma unroll
        for (int o = 0; o < 16; ++o) {
            s_part[wave][o]      = ssum[o];
            s_part[wave][16 + o] = ssq[o];
        }
    }
    __syncthreads();
    if (tid < 32) {
        float t = s_part[0][tid] + s_part[1][tid] +
                  s_part[2][tid] + s_part[3][tid];
        unsafeAtomicAdd(stats + tid, t);
    }
}

// Kernel 3: BatchNorm (batch stats) + LeakyReLU, in place. (unchanged)
__global__ __launch_bounds__(256) void final_kernel(
    float* __restrict__ out,
    const float* __restrict__ stats,
    const float* __restrict__ gamma,
    const float* __restrict__ beta)
{
    int idx = blockIdx.x * 256 + threadIdx.x;      // float4 index
    if (idx >= N_NODES * 4) return;
    int o0 = (idx & 3) << 2;
    const float invN = 1.0f / (float)N_NODES;
    float4 x = *((const float4*)out + idx);
    float xs[4] = {x.x, x.y, x.z, x.w};
    float r[4];
    #pragma unroll
    for (int u = 0; u < 4; ++u) {
        int o = o0 + u;
        float mu = stats[o] * invN;
        float var = fmaxf(stats[16 + o] * invN - mu * mu, 0.0f);
        float y = fmaf(gamma[o] * (xs[u] - mu), rsqrtf(var + EPS), beta[o]);
        r[u] = (y >= 0.0f) ? y : SLOPE * y;
    }
    *((float4*)out + idx) = make_float4(r[0], r[1], r[2], r[3]);
}

extern "C" void kernel_launch(void* const* d_in, const int* in_sizes, int n_in,
                              void* d_out, int out_size, void* d_ws, size_t ws_size,
                              hipStream_t stream)
{
    const float* v = (const float*)d_in[0];
    const float* e = (const float*)d_in[1];
    const int* edge_index = (const int*)d_in[2];
    const float* enet_w = (const float*)d_in[3];
    const float* enet_b = (const float*)d_in[4];
    const float* root = (const float*)d_in[5];
    const float* bias = (const float*)d_in[6];
    const float* gamma = (const float*)d_in[7];
    const float* beta = (const float*)d_in[8];
    float* out = (float*)d_out;

    char* ws = (char*)d_ws;
    float4*       pef   = (float4*)ws;    ws += (size_t)NBUCK * KSUB * SCAP * 16;
    unsigned int* meta  = (unsigned int*)ws;
                                          ws += (size_t)NBUCK * KSUB * SCAP * 4;
    int*          bcur  = (int*)ws;       ws += (size_t)NBUCK * KSUB * 4;
    float*        stats = (float*)ws;

    // zero bcur + stats (contiguous, tiny)
    hipMemsetAsync(bcur, 0, (size_t)NBUCK * KSUB * 4 + 32 * 4, stream);

    bin_kernel<<<NBINB, 256, 0, stream>>>(e, edge_index, bcur, pef, meta);
    gather_bucket_kernel<<<NBUCK, 256, 0, stream>>>(
        v, pef, meta, bcur, enet_w, enet_b, root, bias, out, stats);
    final_kernel<<<(N_NODES * 4 + 255) / 256, 256, 0, stream>>>(
        out, stats, gamma, beta);
}

// Round 19
// 168.255 us; speedup vs baseline: 1.1626x; 1.0064x over previous
//
#include <hip/hip_runtime.h>

#define N_NODES 100000
#define N_EDGES 1000000
#define EPS 1e-5f
#define SLOPE 0.01f
#define NBUCK 391    // ceil(N/256) buckets of 256 consecutive nodes
#define EPB 2560     // edges per bin block
#define NBINB 391    // bin blocks
#define KSUB 8       // sub-cursors per bucket (blockIdx % 8)
#define SCAP 480     // records per (bucket, sub): mean 320 + 8.9 sigma
#define CCAP 3072    // compacted records per bucket in gather LDS

// ---------------------------------------------------------------------------
// ws layout:
//   pef  : NBUCK*KSUB*SCAP*16 B (24.0 MB) edge features, (bucket, sub)-major
//   meta : NBUCK*KSUB*SCAP*4 B  (6.0 MB)  (src<<8 | dst&255) per record
//   bcur : NBUCK*KSUB ints [zeroed]       sub-cursors
//   stats: 32 floats [zeroed]             sum[16], sumsq[16]
// Measured design rules:
//   r5/r6/r16: 1 thread/node is the right gather shape (all lane-splits lose).
//   r8/r9 : grid.sync fusion is NOT coherence-safe on 8-XCD MI355X.
//   r10   : nt stores/L2-bypass regress; plain cached stores optimal.
//   r12-15: same-address atomic RMW = 137 ns; 8-way sub-cursors @391 blocks.
//   r17/18: 20 B/edge bin format is the fastest bin; gather deficit vs r15
//           was the per-edge global pef[r] read (2nd scattered stream).
//   r19   : gather is GRID-limited (1.53 blk/CU) -> LDS is free up to ~80KB.
//           Stage ef in LDS (48KB) in phase A; phase D = 1 contiguous LDS
//           read -> 4 v-line globals + 4 LDS ef reads. ONE global round.
// ---------------------------------------------------------------------------

// Kernel 1: bin edges into (bucket, sub)-major staging. (r17/r18, unchanged)
__global__ __launch_bounds__(256) void bin_kernel(
    const float* __restrict__ efeat,
    const int* __restrict__ edge_index,
    int* __restrict__ bcur,
    float4* __restrict__ pef,
    unsigned int* __restrict__ meta)
{
    __shared__ int s_hist[NBUCK];
    __shared__ int s_base[NBUCK];

    const int tid = threadIdx.x;
    const int ksub = blockIdx.x & (KSUB - 1);
    const int e0 = blockIdx.x * EPB;
    const int e1 = min(e0 + EPB, N_EDGES);

    for (int i = tid; i < NBUCK; i += 256) s_hist[i] = 0;
    __syncthreads();
    for (int eid = e0 + tid; eid < e1; eid += 256) {
        int dst = edge_index[N_EDGES + eid];
        atomicAdd(&s_hist[dst >> 8], 1);
    }
    __syncthreads();

    for (int b = tid; b < NBUCK; b += 256) {
        int c = s_hist[b];
        s_base[b] = c ? atomicAdd(bcur + b * KSUB + ksub, c) : 0;
    }
    __syncthreads();
    for (int i = tid; i < NBUCK; i += 256) s_hist[i] = 0;   // reuse as cursor
    __syncthreads();

    for (int eid = e0 + tid; eid < e1; eid += 256) {
        int src = edge_index[eid];
        int dst = edge_index[N_EDGES + eid];
        float4 ef = *(const float4*)(efeat + (size_t)eid * 4);
        int b = dst >> 8;
        int slot = s_base[b] + atomicAdd(&s_hist[b], 1);
        if (slot < SCAP) {                      // 8.9-sigma margin; never trips
            size_t rec = ((size_t)b * KSUB + ksub) * SCAP + slot;
            pef[rec]  = ef;
            meta[rec] = ((unsigned)src << 8) | (unsigned)(dst & 255);
        }
    }
}

// ---------------------------------------------------------------------------
// Kernel 2: per-bucket fused CSR-build + gather + node transform.
// Phase A stages ef (48 KB LDS) + meta; phase C scatters src*4096+pos into
// CSR order; phase D: contiguous LDS metaS -> 4 v-globals + 4 LDS ef reads.
// LDS ~78.5 KB/block — free, since the grid (391 blocks) is the occupancy cap.
// ---------------------------------------------------------------------------
__global__ __launch_bounds__(256) void gather_bucket_kernel(
    const float* __restrict__ v,
    const float4* __restrict__ pef,
    const unsigned int* __restrict__ meta,
    const int* __restrict__ bcur,
    const float* __restrict__ enet_w,
    const float* __restrict__ enet_b,
    const float* __restrict__ root,
    const float* __restrict__ bias,
    float* __restrict__ out,
    float* __restrict__ stats)
{
    __shared__ float4 s_efA[CCAP];            // 48 KB  ef, compact order
    __shared__ unsigned int s_metaA[CCAP];    // 12 KB  src*4096+pos, compact
    __shared__ unsigned char s_dl[CCAP];      // 3 KB   local dst, compact
    __shared__ unsigned int s_metaS[CCAP];    // 12 KB  src*4096+pos, CSR order
    __shared__ int s_hist[256];
    __shared__ int s_sc[256];
    __shared__ int s_cur[256];
    __shared__ float s_part[4][32];

    const int b = blockIdx.x;
    const int tid = threadIdx.x;

    // A) segment counts (uniform), stage ef + meta -> LDS, histogram
    int ck[KSUB], off[KSUB];
    int cnt = 0;
    #pragma unroll
    for (int k = 0; k < KSUB; ++k) {
        int c = min(bcur[b * KSUB + k], SCAP);
        if (cnt + c > CCAP) c = CCAP - cnt;
        off[k] = cnt;
        ck[k] = c;
        cnt += c;
    }
    s_hist[tid] = 0;
    __syncthreads();
    #pragma unroll
    for (int k = 0; k < KSUB; ++k) {
        size_t segbase = ((size_t)b * KSUB + k) * SCAP;
        for (int i = tid; i < ck[k]; i += 256) {
            unsigned m = meta[segbase + i];
            int pos = off[k] + i;
            int d = (int)(m & 255u);
            s_efA[pos] = pef[segbase + i];
            s_metaA[pos] = (m >> 8) * 4096u + (unsigned)pos;
            s_dl[pos] = (unsigned char)d;
            atomicAdd(&s_hist[d], 1);
        }
    }
    __syncthreads();

    // B) exclusive scan of s_hist
    int deg = s_hist[tid];
    s_sc[tid] = deg;
    __syncthreads();
    #pragma unroll
    for (int offs = 1; offs < 256; offs <<= 1) {
        int t = (tid >= offs) ? s_sc[tid - offs] : 0;
        __syncthreads();
        s_sc[tid] += t;
        __syncthreads();
    }
    int start = s_sc[tid] - deg;
    s_cur[tid] = start;
    __syncthreads();

    // C) scatter SORTED payload: s_metaS[csr_slot] = src*4096 + compact_pos
    for (int i = tid; i < cnt; i += 256) {
        int slot = atomicAdd(&s_cur[s_dl[i]], 1);
        s_metaS[slot] = s_metaA[i];
    }
    __syncthreads();

    // D) gather, x4 ILP unroll. Per chunk: 4 contiguous LDS metaS reads ->
    //    4 independent v-line globals + 4 LDS ef reads. One global round.
    int n = b * 256 + tid;
    bool active = (n < N_NODES);

    float acc[80];
    #pragma unroll
    for (int i = 0; i < 80; ++i) acc[i] = 0.0f;

    int j = 0;
    for (; j + 4 <= deg; j += 4) {
        unsigned m0 = s_metaS[start + j + 0];
        unsigned m1 = s_metaS[start + j + 1];
        unsigned m2 = s_metaS[start + j + 2];
        unsigned m3 = s_metaS[start + j + 3];
        int s0 = (int)(m0 >> 12), p0 = (int)(m0 & 4095u);
        int s1 = (int)(m1 >> 12), p1 = (int)(m1 & 4095u);
        int s2 = (int)(m2 >> 12), p2 = (int)(m2 & 4095u);
        int s3 = (int)(m3 >> 12), p3 = (int)(m3 & 4095u);
        const float4* vr0 = (const float4*)(v + (size_t)s0 * 16);
        const float4* vr1 = (const float4*)(v + (size_t)s1 * 16);
        const float4* vr2 = (const float4*)(v + (size_t)s2 * 16);
        const float4* vr3 = (const float4*)(v + (size_t)s3 * 16);
        float4 ef0 = s_efA[p0];
        float4 ef1 = s_efA[p1];
        float4 ef2 = s_efA[p2];
        float4 ef3 = s_efA[p3];
        #pragma unroll
        for (int i = 0; i < 4; ++i) {
            float4 a = vr0[i], bb = vr1[i], c = vr2[i], d = vr3[i];
            acc[     i*4+0] += (a.x + bb.x) + (c.x + d.x);
            acc[     i*4+1] += (a.y + bb.y) + (c.y + d.y);
            acc[     i*4+2] += (a.z + bb.z) + (c.z + d.z);
            acc[     i*4+3] += (a.w + bb.w) + (c.w + d.w);
            acc[16 + i*4+0] = fmaf(ef0.x, a.x, fmaf(ef1.x, bb.x,
                              fmaf(ef2.x, c.x, fmaf(ef3.x, d.x, acc[16 + i*4+0]))));
            acc[16 + i*4+1] = fmaf(ef0.x, a.y, fmaf(ef1.x, bb.y,
                              fmaf(ef2.x, c.y, fmaf(ef3.x, d.y, acc[16 + i*4+1]))));
            acc[16 + i*4+2] = fmaf(ef0.x, a.z, fmaf(ef1.x, bb.z,
                              fmaf(ef2.x, c.z, fmaf(ef3.x, d.z, acc[16 + i*4+2]))));
            acc[16 + i*4+3] = fmaf(ef0.x, a.w, fmaf(ef1.x, bb.w,
                              fmaf(ef2.x, c.w, fmaf(ef3.x, d.w, acc[16 + i*4+3]))));
            acc[32 + i*4+0] = fmaf(ef0.y, a.x, fmaf(ef1.y, bb.x,
                              fmaf(ef2.y, c.x, fmaf(ef3.y, d.x, acc[32 + i*4+0]))));
            acc[32 + i*4+1] = fmaf(ef0.y, a.y, fmaf(ef1.y, bb.y,
                              fmaf(ef2.y, c.y, fmaf(ef3.y, d.y, acc[32 + i*4+1]))));
            acc[32 + i*4+2] = fmaf(ef0.y, a.z, fmaf(ef1.y, bb.z,
                              fmaf(ef2.y, c.z, fmaf(ef3.y, d.z, acc[32 + i*4+2]))));
            acc[32 + i*4+3] = fmaf(ef0.y, a.w, fmaf(ef1.y, bb.w,
                              fmaf(ef2.y, c.w, fmaf(ef3.y, d.w, acc[32 + i*4+3]))));
            acc[48 + i*4+0] = fmaf(ef0.z, a.x, fmaf(ef1.z, bb.x,
                              fmaf(ef2.z, c.x, fmaf(ef3.z, d.x, acc[48 + i*4+0]))));
            acc[48 + i*4+1] = fmaf(ef0.z, a.y, fmaf(ef1.z, bb.y,
                              fmaf(ef2.z, c.y, fmaf(ef3.z, d.y, acc[48 + i*4+1]))));
            acc[48 + i*4+2] = fmaf(ef0.z, a.z, fmaf(ef1.z, bb.z,
                              fmaf(ef2.z, c.z, fmaf(ef3.z, d.z, acc[48 + i*4+2]))));
            acc[48 + i*4+3] = fmaf(ef0.z, a.w, fmaf(ef1.z, bb.w,
                              fmaf(ef2.z, c.w, fmaf(ef3.z, d.w, acc[48 + i*4+3]))));
            acc[64 + i*4+0] = fmaf(ef0.w, a.x, fmaf(ef1.w, bb.x,
                              fmaf(ef2.w, c.x, fmaf(ef3.w, d.x, acc[64 + i*4+0]))));
            acc[64 + i*4+1] = fmaf(ef0.w, a.y, fmaf(ef1.w, bb.y,
                              fmaf(ef2.w, c.y, fmaf(ef3.w, d.y, acc[64 + i*4+1]))));
            acc[64 + i*4+2] = fmaf(ef0.w, a.z, fmaf(ef1.w, bb.z,
                              fmaf(ef2.w, c.z, fmaf(ef3.w, d.z, acc[64 + i*4+2]))));
            acc[64 + i*4+3] = fmaf(ef0.w, a.w, fmaf(ef1.w, bb.w,
                              fmaf(ef2.w, c.w, fmaf(ef3.w, d.w, acc[64 + i*4+3]))));
        }
    }
    for (; j < deg; ++j) {
        unsigned m0 = s_metaS[start + j];
        int s0 = (int)(m0 >> 12), p0 = (int)(m0 & 4095u);
        const float4* vr = (const float4*)(v + (size_t)s0 * 16);
        float4 ef = s_efA[p0];
        #pragma unroll
        for (int i = 0; i < 4; ++i) {
            float4 a = vr[i];
            acc[     i*4+0] += a.x;
            acc[     i*4+1] += a.y;
            acc[     i*4+2] += a.z;
            acc[     i*4+3] += a.w;
            acc[16 + i*4+0] = fmaf(ef.x, a.x, acc[16 + i*4+0]);
            acc[16 + i*4+1] = fmaf(ef.x, a.y, acc[16 + i*4+1]);
            acc[16 + i*4+2] = fmaf(ef.x, a.z, acc[16 + i*4+2]);
            acc[16 + i*4+3] = fmaf(ef.x, a.w, acc[16 + i*4+3]);
            acc[32 + i*4+0] = fmaf(ef.y, a.x, acc[32 + i*4+0]);
            acc[32 + i*4+1] = fmaf(ef.y, a.y, acc[32 + i*4+1]);
            acc[32 + i*4+2] = fmaf(ef.y, a.z, acc[32 + i*4+2]);
            acc[32 + i*4+3] = fmaf(ef.y, a.w, acc[32 + i*4+3]);
            acc[48 + i*4+0] = fmaf(ef.z, a.x, acc[48 + i*4+0]);
            acc[48 + i*4+1] = fmaf(ef.z, a.y, acc[48 + i*4+1]);
            acc[48 + i*4+2] = fmaf(ef.z, a.z, acc[48 + i*4+2]);
            acc[48 + i*4+3] = fmaf(ef.z, a.w, acc[48 + i*4+3]);
            acc[64 + i*4+0] = fmaf(ef.w, a.x, acc[64 + i*4+0]);
            acc[64 + i*4+1] = fmaf(ef.w, a.y, acc[64 + i*4+1]);
            acc[64 + i*4+2] = fmaf(ef.w, a.z, acc[64 + i*4+2]);
            acc[64 + i*4+3] = fmaf(ef.w, a.w, acc[64 + i*4+3]);
        }
    }

    float val[16];
    if (active) {
        float vn[16];
        #pragma unroll
        for (int i = 0; i < 4; ++i) {
            float4 tv = *(const float4*)(v + (size_t)n * 16 + i * 4);
            vn[4*i+0] = tv.x; vn[4*i+1] = tv.y;
            vn[4*i+2] = tv.z; vn[4*i+3] = tv.w;
        }
        float scale = 1.0f / fmaxf((float)deg, 1.0f);
        #pragma unroll
        for (int o = 0; o < 16; ++o) {
            float a = 0.0f;
            #pragma unroll
            for (int i = 0; i < 16; ++i) {
                a = fmaf(acc[i], enet_b[i * 16 + o], a);           // S0 * B
                #pragma unroll
                for (int k = 0; k < 4; ++k)
                    a = fmaf(acc[16 + k * 16 + i],
                             enet_w[(i * 16 + o) * 4 + k], a);     // Sk * Wk
            }
            a = fmaf(a, scale, bias[o]);
            #pragma unroll
            for (int i = 0; i < 16; ++i)
                a = fmaf(vn[i], root[i * 16 + o], a);
            val[o] = a;
        }
        #pragma unroll
        for (int i = 0; i < 4; ++i)
            *(float4*)(out + (size_t)n * 16 + i * 4) =
                make_float4(val[4*i+0], val[4*i+1], val[4*i+2], val[4*i+3]);
    } else {
        #pragma unroll
        for (int o = 0; o < 16; ++o) val[o] = 0.0f;
    }

    // batch-stat reduction: wave butterfly -> LDS -> device atomic
    float ssum[16], ssq[16];
    #pragma unroll
    for (int o = 0; o < 16; ++o) {
        float a = val[o];
        float bsq = a * a;
        #pragma unroll
        for (int m = 1; m < 64; m <<= 1) {
            a += __shfl_xor(a, m, 64);
            bsq += __shfl_xor(bsq, m, 64);
        }
        ssum[o] = a; ssq[o] = bsq;
    }
    int wave = tid >> 6;
    int lane = tid & 63;
    if (lane == 0) {
        #pragma unroll
        for (int o = 0; o < 16; ++o) {
            s_part[wave][o]      = ssum[o];
            s_part[wave][16 + o] = ssq[o];
        }
    }
    __syncthreads();
    if (tid < 32) {
        float t = s_part[0][tid] + s_part[1][tid] +
                  s_part[2][tid] + s_part[3][tid];
        unsafeAtomicAdd(stats + tid, t);
    }
}

// Kernel 3: BatchNorm (batch stats) + LeakyReLU, in place. (unchanged)
__global__ __launch_bounds__(256) void final_kernel(
    float* __restrict__ out,
    const float* __restrict__ stats,
    const float* __restrict__ gamma,
    const float* __restrict__ beta)
{
    int idx = blockIdx.x * 256 + threadIdx.x;      // float4 index
    if (idx >= N_NODES * 4) return;
    int o0 = (idx & 3) << 2;
    const float invN = 1.0f / (float)N_NODES;
    float4 x = *((const float4*)out + idx);
    float xs[4] = {x.x, x.y, x.z, x.w};
    float r[4];
    #pragma unroll
    for (int u = 0; u < 4; ++u) {
        int o = o0 + u;
        float mu = stats[o] * invN;
        float var = fmaxf(stats[16 + o] * invN - mu * mu, 0.0f);
        float y = fmaf(gamma[o] * (xs[u] - mu), rsqrtf(var + EPS), beta[o]);
        r[u] = (y >= 0.0f) ? y : SLOPE * y;
    }
    *((float4*)out + idx) = make_float4(r[0], r[1], r[2], r[3]);
}

extern "C" void kernel_launch(void* const* d_in, const int* in_sizes, int n_in,
                              void* d_out, int out_size, void* d_ws, size_t ws_size,
                              hipStream_t stream)
{
    const float* v = (const float*)d_in[0];
    const float* e = (const float*)d_in[1];
    const int* edge_index = (const int*)d_in[2];
    const float* enet_w = (const float*)d_in[3];
    const float* enet_b = (const float*)d_in[4];
    const float* root = (const float*)d_in[5];
    const float* bias = (const float*)d_in[6];
    const float* gamma = (const float*)d_in[7];
    const float* beta = (const float*)d_in[8];
    float* out = (float*)d_out;

    char* ws = (char*)d_ws;
    float4*       pef   = (float4*)ws;    ws += (size_t)NBUCK * KSUB * SCAP * 16;
    unsigned int* meta  = (unsigned int*)ws;
                                          ws += (size_t)NBUCK * KSUB * SCAP * 4;
    int*          bcur  = (int*)ws;       ws += (size_t)NBUCK * KSUB * 4;
    float*        stats = (float*)ws;

    // zero bcur + stats (contiguous, tiny)
    hipMemsetAsync(bcur, 0, (size_t)NBUCK * KSUB * 4 + 32 * 4, stream);

    bin_kernel<<<NBINB, 256, 0, stream>>>(e, edge_index, bcur, pef, meta);
    gather_bucket_kernel<<<NBUCK, 256, 0, stream>>>(
        v, pef, meta, bcur, enet_w, enet_b, root, bias, out, stats);
    final_kernel<<<(N_NODES * 4 + 255) / 256, 256, 0, stream>>>(
        out, stats, gamma, beta);
}